// Round 10
// baseline (175.820 us; speedup 1.0000x reference)
//
#include <hip/hip_runtime.h>
#include <math.h>

typedef _Float16 f16;
typedef _Float16 f16x2 __attribute__((ext_vector_type(2)));
typedef _Float16 f16x4 __attribute__((ext_vector_type(4)));
typedef _Float16 f16x8 __attribute__((ext_vector_type(8)));
typedef float f32x4 __attribute__((ext_vector_type(4)));

#define AS1 __attribute__((address_space(1)))
#define AS3 __attribute__((address_space(3)))

__device__ __forceinline__ void gload_lds16(const void* g, void* l) {
    __builtin_amdgcn_global_load_lds((AS1 void*)(g), (AS3 void*)(l), 16, 0, 0);
}

// fast transcendentals: v_exp_f32 (exp2) + v_rcp_f32, ~1 ulp, correct saturation
__device__ __forceinline__ float sigmoid_fast(float v) {
    return __builtin_amdgcn_rcpf(1.f + __builtin_amdgcn_exp2f(-1.44269504f * v));
}
__device__ __forceinline__ float tanh_fast(float v) {
    return 1.f - 2.f * __builtin_amdgcn_rcpf(1.f + __builtin_amdgcn_exp2f(2.88539008f * v));
}

// ---------------- LDS-tiled transpose+cast: Wt[n][k] = (f16)W[k][n], 64x64 tiles ----------------
__global__ __launch_bounds__(256) void tpose_kernel(const float* __restrict__ W, f16* __restrict__ Wt,
                                                    int K, int N) {
    __shared__ float T[64][65];
    const int k0 = blockIdx.x * 64, n0 = blockIdx.y * 64;
    const int tid = threadIdx.x;
    const int rr = tid >> 4, cc = (tid & 15) * 4;
#pragma unroll
    for (int p = 0; p < 4; ++p) {
        int k = rr + p * 16;
        float4 v = *(const float4*)&W[(size_t)(k0 + k) * N + n0 + cc];
        T[k][cc] = v.x; T[k][cc + 1] = v.y; T[k][cc + 2] = v.z; T[k][cc + 3] = v.w;
    }
    __syncthreads();
#pragma unroll
    for (int p = 0; p < 4; ++p) {
        int n = rr + p * 16;
        f16x4 h;
        h[0] = (f16)T[cc][n]; h[1] = (f16)T[cc + 1][n];
        h[2] = (f16)T[cc + 2][n]; h[3] = (f16)T[cc + 3][n];
        *(f16x4*)&Wt[(size_t)(n0 + n) * K + k0 + cc] = h;
    }
}

// ---------------- embedding cast to f16, padded rows zeroed ----------------
__global__ __launch_bounds__(256) void ecast_kernel(const float* __restrict__ emb, f16* __restrict__ E) {
    int r = blockIdx.x * 4 + (threadIdx.x >> 6);
    int c = (threadIdx.x & 63) * 4;
    float4 v = make_float4(0.f, 0.f, 0.f, 0.f);
    if (r < 10000) v = *(const float4*)&emb[(size_t)r * 256 + c];
    f16x4 h;
    h[0] = (f16)v.x; h[1] = (f16)v.y; h[2] = (f16)v.z; h[3] = (f16)v.w;
    *(f16x4*)&E[(size_t)r * 256 + c] = h;
}

// ---------------- epilogue C-tile write to LDS (swizzled, activation applied) ----------------
template <int ACT>
__device__ __forceinline__ void cs_write(f16* Cs, const f32x4 (&acc)[4][4], const float* bp,
                                         int wr, int wc, int lo16, int hi4) {
#pragma unroll
    for (int n = 0; n < 4; ++n) {
        int col = wc * 64 + n * 16 + lo16;
        float b = bp ? bp[col] : 0.f;
        int ch = col >> 3, el = col & 7;
#pragma unroll
        for (int m = 0; m < 4; ++m) {
#pragma unroll
            for (int j = 0; j < 4; ++j) {
                int row = wr * 64 + m * 16 + hi4 * 4 + j;
                float v = acc[m][n][j] + b;
                float o = (ACT == 0) ? fmaxf(v, 0.f) : ((ACT == 1) ? sigmoid_fast(v) : tanh_fast(v));
                int sw = ch ^ (row & 15);
                Cs[row * 128 + sw * 8 + el] = (f16)o;
            }
        }
    }
}

// ---------------- GEMM: C = act(A @ Bt^T + bias), 128x128 tile, templated BK, double-buffered ----
// BK=32 -> 32 KB LDS -> 5 blocks/CU (vs 2 at BK=64): tail-free grids + deep cross-wave overlap.
// MODE 0 (N=5120): col<2048 relu+b1->O0[.,2048];
//   cols 2048..4095 are W3/W4 INTERLEAVED in 16-col groups (remapped at stage time):
//     even fragment = sigmoid(.+b3), odd fragment = tanh(.+b4); epilogue writes p=i*g -> O1 (Pt, 1024)
//   col>=4096 relu (no bias) -> O3 (Ut)
// MODE 1: tanh+bias epilogue (N=1024) -> O0 stride 1024
template <int MODE, int BK>
__global__ __launch_bounds__(256) void gemm_main(
    const f16* __restrict__ A, const f16* __restrict__ Bt, int N, int K, int CT,
    const float* __restrict__ bb1, const float* __restrict__ bb3, const float* __restrict__ bb4,
    f16* __restrict__ O0, f16* __restrict__ O1, f16* __restrict__ O3) {
    constexpr int SLOTS = BK / 8;            // 16B slots per LDS row
    constexpr int SMASK = SLOTS - 1;
    constexpr int LOG2S = (BK == 32) ? 2 : 3;
    constexpr int ITS = BK / 16;             // staging iters (256 thr, 16B each)
    __shared__ f16 SM[512 * BK];             // 2 bufs x (As 128xBK | Bs 128xBK); reused as Cs
    f16* Cs = SM;                            // BK>=32 -> >=32KB, fits 128x128 f16 C-tile
    // bijective XCD remap (m204), then row-major decode: consecutive wg share A-panel
    const int nwg = gridDim.x, orig = blockIdx.x;
    const int q = nwg >> 3, rm = nwg & 7;
    const int xcd = orig & 7, loc = orig >> 3;
    const int wg = (xcd < rm ? xcd * (q + 1) : rm * (q + 1) + (xcd - rm) * q) + loc;
    const int rowT = wg / CT, colT = wg - rowT * CT;
    const int row0 = rowT * 128, col0 = colT * 128;

    const int tid = threadIdx.x;
    const int wave = tid >> 6, lane = tid & 63;
    const int wr = wave >> 1, wc = wave & 1;
    const int lo16 = lane & 15, hi4 = lane >> 4;

    const bool PM = (MODE == 0) && (col0 >= 2048) && (col0 < 4096);  // block-uniform

    f32x4 acc[4][4] = {};

    auto stage = [&](int buf, int k0) {
        f16* As = SM + buf * 256 * BK;
        f16* Bs = As + 128 * BK;
#pragma unroll
        for (int it = 0; it < ITS; ++it) {
            int c = it * 256 + wave * 64 + lane;   // 16B chunk id, lane-contiguous per wave
            int r = c >> LOG2S, sl = c & SMASK;
            int kc = ((sl ^ (r & SMASK)) << 3);    // pre-swizzled global source (rule #21)
            int brow = col0 + r;
            if (PM) {                               // W3/W4 16-col interleave remap
                int qc = col0 - 2048 + r;
                int grp = qc >> 5, q2 = qc & 31;
                brow = (q2 < 16) ? (2048 + grp * 16 + q2) : (3072 + grp * 16 + (q2 - 16));
            }
            gload_lds16(A  + (size_t)(row0 + r) * K + (k0 + kc), &As[c * 8]);
            gload_lds16(Bt + (size_t)brow * K + (k0 + kc), &Bs[c * 8]);
        }
    };

    const int nt = K / BK;
    stage(0, 0);
    __syncthreads();                               // buf0 ready
    for (int t = 0; t < nt; ++t) {
        if (t + 1 < nt) stage((t + 1) & 1, (t + 1) * BK);   // prefetch in flight during MFMA
        const f16* As = SM + (t & 1) * 256 * BK;
        const f16* Bs = As + 128 * BK;
#pragma unroll
        for (int kk = 0; kk < BK; kk += 32) {
            const int s0 = (kk >> 3) + hi4;
            const int sw = s0 ^ (lo16 & SMASK);    // read-side swizzle (same involution)
            f16x8 af[4], bf[4];
#pragma unroll
            for (int m = 0; m < 4; ++m)
                af[m] = *(const f16x8*)&As[(wr * 64 + m * 16 + lo16) * BK + (sw << 3)];
#pragma unroll
            for (int n = 0; n < 4; ++n)
                bf[n] = *(const f16x8*)&Bs[(wc * 64 + n * 16 + lo16) * BK + (sw << 3)];
#pragma unroll
            for (int m = 0; m < 4; ++m)
#pragma unroll
                for (int n = 0; n < 4; ++n)
                    acc[m][n] = __builtin_amdgcn_mfma_f32_16x16x32_f16(af[m], bf[n], acc[m][n], 0, 0, 0);
        }
        __syncthreads();   // single barrier/iter: drains prefetch (covered by MFMA) + seals reads
    }

    if (PM) {
        // p-fusion epilogue: p = sigmoid(acc_even + b3) * tanh(acc_odd + b4), 128x64 tile
        const int c = (col0 - 2048) >> 7;
#pragma unroll
        for (int pair = 0; pair < 2; ++pair) {
            int colg = 16 * (4 * c + 2 * wc + pair) + lo16;   // global Pt col
            float bi = bb3[colg], bg = bb4[colg];
            int colL = wc * 32 + pair * 16 + lo16;            // local col in 64-wide tile
#pragma unroll
            for (int m = 0; m < 4; ++m)
#pragma unroll
                for (int j = 0; j < 4; ++j) {
                    int row = wr * 64 + m * 16 + hi4 * 4 + j;
                    float pi = sigmoid_fast(acc[m][2 * pair][j] + bi);
                    float pg = tanh_fast(acc[m][2 * pair + 1][j] + bg);
                    Cs[row * 64 + 8 * ((colL >> 3) ^ (row & 7)) + (colL & 7)] = (f16)(pi * pg);
                }
        }
        __syncthreads();
        const int pcol0 = (col0 - 2048) >> 1;
#pragma unroll
        for (int it = 0; it < 4; ++it) {
            int idx = it * 256 + tid;
            int row = idx >> 3, ch = idx & 7;
            f16x8 v = *(const f16x8*)&Cs[row * 64 + 8 * (ch ^ (row & 7))];
            *(f16x8*)&O1[(size_t)(row0 + row) * 1024 + pcol0 + ch * 8] = v;
        }
        return;
    }

    // block-uniform epilogue params (non-interleaved tiles)
    f16* Oe; size_t ostr; const float* bp; int act;
    if (MODE == 1)          { Oe = O0 + col0;          ostr = 1024; bp = bb1 + col0;          act = 2; }
    else if (col0 < 2048)   { Oe = O0 + col0;          ostr = 2048; bp = bb1 + col0;          act = 0; }
    else                    { Oe = O3 + (col0 - 4096); ostr = 1024; bp = nullptr;             act = 0; }

    if (act == 0) cs_write<0>(Cs, acc, bp, wr, wc, lo16, hi4);
    else          cs_write<2>(Cs, acc, bp, wr, wc, lo16, hi4);
    __syncthreads();

    // coalesced store: 8 x f16x8 per thread, 1KB contiguous per wave
#pragma unroll
    for (int it = 0; it < 8; ++it) {
        int idx = it * 256 + tid;
        int row = idx >> 4, ch = idx & 15;
        int sw = ch ^ (row & 15);
        f16x8 v = *(const f16x8*)&Cs[row * 128 + sw * 8];
        *(f16x8*)&Oe[(size_t)(row0 + row) * ostr + ch * 8] = v;
    }
}

// ---------------- scan over T, XCD-sliced: block = (batch b, unit-slice x of 128) ----------------
// blockIdx = b*8 + x -> round-robin dispatch pins slice x to XCD x (L2 affinity).
// Branch-free 16-slot / 12-deep static software pipeline: loads for step t+12 are issued
// unconditionally (token buffer zero-padded) 12 steps before use; all slot indices are
// compile-time constants (main loop unrolled by 16 so t&15 == k).
__global__ __launch_bounds__(64) void scan_slice_kernel(
    const int* __restrict__ tokens, const f16* __restrict__ Mt, const f16* __restrict__ Pt,
    const f16* __restrict__ Ut, const float* __restrict__ state0,
    const float* __restrict__ Wout, float* __restrict__ partial) {
    __shared__ int toks[256];
    const int bid = blockIdx.x;
    const int b = bid >> 3, x = bid & 7;
    const int lane = threadIdx.x;
    for (int t = lane; t < 256; t += 64) toks[t] = (t < 250) ? tokens[b * 250 + t] : 0;
    __syncthreads();

    const int u0 = x * 128 + lane * 2;
    float2 sv = *(const float2*)&state0[(size_t)b * 1024 + u0];
    float s0 = sv.x, s1 = sv.y;

    f16x2 m[16], p[16], u[16];
#pragma unroll
    for (int k = 0; k < 12; ++k) {   // preload t=0..11 into slots 0..11
        size_t nb = (size_t)toks[k] * 1024 + u0;
        m[k] = *(const f16x2*)&Mt[nb];
        p[k] = *(const f16x2*)&Pt[nb];
        u[k] = *(const f16x2*)&Ut[nb];
    }

    // main: t = 0..239 (15 x 16 unrolled, all slots static); loads target t+12
    for (int tb = 0; tb < 240; tb += 16) {
#pragma unroll
        for (int k = 0; k < 16; ++k) {
            const int ls = (k + 12) & 15;        // compile-time slot for t+12
            size_t nb = (size_t)toks[tb + k + 12] * 1024 + u0;
            m[ls] = *(const f16x2*)&Mt[nb];
            p[ls] = *(const f16x2*)&Pt[nb];
            u[ls] = *(const f16x2*)&Ut[nb];
            float y0 = fmaxf((float)m[k][0] * s0 + (float)p[k][0], 0.f);
            s0 = fmaxf((float)u[k][0] + y0, 0.f);
            float y1 = fmaxf((float)m[k][1] * s1 + (float)p[k][1], 0.f);
            s1 = fmaxf((float)u[k][1] + y1, 0.f);
        }
    }
    // tail: t = 240..249 (slots 0..9, already loaded at t=228..237)
#pragma unroll
    for (int k = 0; k < 10; ++k) {
        float y0 = fmaxf((float)m[k][0] * s0 + (float)p[k][0], 0.f);
        s0 = fmaxf((float)u[k][0] + y0, 0.f);
        float y1 = fmaxf((float)m[k][1] * s1 + (float)p[k][1], 0.f);
        s1 = fmaxf((float)u[k][1] + y1, 0.f);
    }

    float2 wv = *(const float2*)&Wout[u0];
    float part = s0 * wv.x + s1 * wv.y;
#pragma unroll
    for (int o = 32; o > 0; o >>= 1) part += __shfl_down(part, o, 64);
    if (lane == 0) partial[bid] = part;
}

// ---------------- final reduce: out[b] = sigmoid(sum_x partial[b*8+x] + bout) ----------------
__global__ __launch_bounds__(256) void final_kernel(const float* __restrict__ partial,
                                                    const float* __restrict__ bout,
                                                    float* __restrict__ out) {
    int b = threadIdx.x;
    float tot = bout[0];
#pragma unroll
    for (int w = 0; w < 8; ++w) tot += partial[b * 8 + w];
    out[b] = sigmoid_fast(tot);
}

extern "C" void kernel_launch(void* const* d_in, const int* in_sizes, int n_in,
                              void* d_out, int out_size, void* d_ws, size_t ws_size,
                              hipStream_t stream) {
    const int*   tokens = (const int*)  d_in[0];
    const float* emb    = (const float*)d_in[1];
    const float* W1     = (const float*)d_in[2];
    const float* b1     = (const float*)d_in[3];
    const float* W2     = (const float*)d_in[4];
    const float* b2     = (const float*)d_in[5];
    const float* W3     = (const float*)d_in[6];
    const float* b3     = (const float*)d_in[7];
    const float* W4     = (const float*)d_in[8];
    const float* b4     = (const float*)d_in[9];
    const float* W5     = (const float*)d_in[10];
    const float* Wout   = (const float*)d_in[11];
    const float* bout   = (const float*)d_in[12];
    const float* state0 = (const float*)d_in[13];
    float* out = (float*)d_out;

    const int RP = 10112;  // 79 * 128, padded vocab rows

    char* ws = (char*)d_ws;
    size_t off = 0;
    auto alloc = [&](size_t bytes) -> void* {
        void* p = ws + off;
        off += (bytes + 255) & ~(size_t)255;
        return p;
    };
    f16* WtQ = (f16*)alloc((size_t)5120 * 256 * 2);   // W1|W3|W4|W5 transposed [5120][256]
    f16* Wt2 = (f16*)alloc((size_t)1024 * 2048 * 2);
    f16* E   = (f16*)alloc((size_t)RP * 256 * 2);
    f16* Rb  = (f16*)alloc((size_t)RP * 2048 * 2);
    f16* Mt  = (f16*)alloc((size_t)RP * 1024 * 2);
    f16* Pt  = (f16*)alloc((size_t)RP * 1024 * 2);
    f16* Ut  = (f16*)alloc((size_t)RP * 1024 * 2);
    float* partial = (float*)alloc((size_t)2048 * 4);
    (void)ws_size; (void)in_sizes; (void)n_in; (void)out_size;

    // weights -> f16 transposed [N][K] (LDS-tiled, coalesced both ways)
    tpose_kernel<<<dim3(4, 32),  256, 0, stream>>>(W1, WtQ,               256, 2048);
    tpose_kernel<<<dim3(4, 16),  256, 0, stream>>>(W3, WtQ + 2048 * 256,  256, 1024);
    tpose_kernel<<<dim3(4, 16),  256, 0, stream>>>(W4, WtQ + 3072 * 256,  256, 1024);
    tpose_kernel<<<dim3(4, 16),  256, 0, stream>>>(W5, WtQ + 4096 * 256,  256, 1024);
    tpose_kernel<<<dim3(32, 16), 256, 0, stream>>>(W2, Wt2,              2048, 1024);
    ecast_kernel<<<RP / 4, 256, 0, stream>>>(emb, E);

    // fused per-vocab tables: E @ [W1 | W3/W4 interleaved | W5]  (N=5120, K=256)
    gemm_main<0, 32><<<(RP / 128) * (5120 / 128), 256, 0, stream>>>(
        E, WtQ, 5120, 256, 5120 / 128, b1, b3, b4, Rb, Pt, Ut);
    // Mt = tanh(relu(...) @ W2 + b2)  (N=1024, K=2048)  -- BK=32: whole grid co-resident
    gemm_main<1, 32><<<(RP / 128) * (1024 / 128), 256, 0, stream>>>(
        Rb, Wt2, 1024, 2048, 1024 / 128, b2, nullptr, nullptr, Mt, nullptr, nullptr);

    // scan (XCD-sliced, deep-pipelined) + final projection reduce
    scan_slice_kernel<<<2048, 64, 0, stream>>>(tokens, Mt, Pt, Ut, state0, Wout, partial);
    final_kernel<<<1, 256, 0, stream>>>(partial, bout, out);
}

// Round 11
// 173.566 us; speedup vs baseline: 1.0130x; 1.0130x over previous
//
#include <hip/hip_runtime.h>
#include <math.h>

typedef _Float16 f16;
typedef _Float16 f16x2 __attribute__((ext_vector_type(2)));
typedef _Float16 f16x4 __attribute__((ext_vector_type(4)));
typedef _Float16 f16x8 __attribute__((ext_vector_type(8)));
typedef float f32x4 __attribute__((ext_vector_type(4)));

#define AS1 __attribute__((address_space(1)))
#define AS3 __attribute__((address_space(3)))

__device__ __forceinline__ void gload_lds16(const void* g, void* l) {
    __builtin_amdgcn_global_load_lds((AS1 void*)(g), (AS3 void*)(l), 16, 0, 0);
}

// fast transcendentals: v_exp_f32 (exp2) + v_rcp_f32, ~1 ulp, correct saturation
__device__ __forceinline__ float sigmoid_fast(float v) {
    return __builtin_amdgcn_rcpf(1.f + __builtin_amdgcn_exp2f(-1.44269504f * v));
}
__device__ __forceinline__ float tanh_fast(float v) {
    return 1.f - 2.f * __builtin_amdgcn_rcpf(1.f + __builtin_amdgcn_exp2f(2.88539008f * v));
}

// ---------------- LDS-tiled transpose+cast: Wt[n][k] = (f16)W[k][n], 64x64 tiles ----------------
__global__ __launch_bounds__(256) void tpose_kernel(const float* __restrict__ W, f16* __restrict__ Wt,
                                                    int K, int N) {
    __shared__ float T[64][65];
    const int k0 = blockIdx.x * 64, n0 = blockIdx.y * 64;
    const int tid = threadIdx.x;
    const int rr = tid >> 4, cc = (tid & 15) * 4;
#pragma unroll
    for (int p = 0; p < 4; ++p) {
        int k = rr + p * 16;
        float4 v = *(const float4*)&W[(size_t)(k0 + k) * N + n0 + cc];
        T[k][cc] = v.x; T[k][cc + 1] = v.y; T[k][cc + 2] = v.z; T[k][cc + 3] = v.w;
    }
    __syncthreads();
#pragma unroll
    for (int p = 0; p < 4; ++p) {
        int n = rr + p * 16;
        f16x4 h;
        h[0] = (f16)T[cc][n]; h[1] = (f16)T[cc + 1][n];
        h[2] = (f16)T[cc + 2][n]; h[3] = (f16)T[cc + 3][n];
        *(f16x4*)&Wt[(size_t)(n0 + n) * K + k0 + cc] = h;
    }
}

// ---------------- embedding cast to f16, padded rows zeroed ----------------
__global__ __launch_bounds__(256) void ecast_kernel(const float* __restrict__ emb, f16* __restrict__ E) {
    int r = blockIdx.x * 4 + (threadIdx.x >> 6);
    int c = (threadIdx.x & 63) * 4;
    float4 v = make_float4(0.f, 0.f, 0.f, 0.f);
    if (r < 10000) v = *(const float4*)&emb[(size_t)r * 256 + c];
    f16x4 h;
    h[0] = (f16)v.x; h[1] = (f16)v.y; h[2] = (f16)v.z; h[3] = (f16)v.w;
    *(f16x4*)&E[(size_t)r * 256 + c] = h;
}

// ---------------- epilogue C-tile write to LDS (swizzled, activation applied) ----------------
template <int ACT>
__device__ __forceinline__ void cs_write(f16* Cs, const f32x4 (&acc)[4][4], const float* bp,
                                         int wr, int wc, int lo16, int hi4) {
#pragma unroll
    for (int n = 0; n < 4; ++n) {
        int col = wc * 64 + n * 16 + lo16;
        float b = bp ? bp[col] : 0.f;
        int ch = col >> 3, el = col & 7;
#pragma unroll
        for (int m = 0; m < 4; ++m) {
#pragma unroll
            for (int j = 0; j < 4; ++j) {
                int row = wr * 64 + m * 16 + hi4 * 4 + j;
                float v = acc[m][n][j] + b;
                float o = (ACT == 0) ? fmaxf(v, 0.f) : ((ACT == 1) ? sigmoid_fast(v) : tanh_fast(v));
                int sw = ch ^ (row & 15);
                Cs[row * 128 + sw * 8 + el] = (f16)o;
            }
        }
    }
}

// ---------------- GEMM: C = act(A @ Bt^T + bias), 128x128 tile, templated BK, double-buffered ----
// BK=32 -> 32 KB LDS -> 5 blocks/CU. Swizzle is row-PHASE aware: a BK=32 row spans 64 B
// (2 bank phases), so slot-XOR uses (row>>1)&3 — even rows cover all 4 slots exactly twice
// (2-way = free, m136); plain row&3 gave 4-way conflicts (3.2M measured, round 10).
// MODE 0 (N=5120): col<2048 relu+b1->O0[.,2048];
//   cols 2048..4095 are W3/W4 INTERLEAVED in 16-col groups (remapped at stage time):
//     even fragment = sigmoid(.+b3), odd fragment = tanh(.+b4); epilogue writes p=i*g -> O1 (Pt, 1024)
//   col>=4096 relu (no bias) -> O3 (Ut)
// MODE 1: tanh+bias epilogue (N=1024) -> O0 stride 1024
template <int MODE, int BK>
__global__ __launch_bounds__(256) void gemm_main(
    const f16* __restrict__ A, const f16* __restrict__ Bt, int N, int K, int CT,
    const float* __restrict__ bb1, const float* __restrict__ bb3, const float* __restrict__ bb4,
    f16* __restrict__ O0, f16* __restrict__ O1, f16* __restrict__ O3) {
    constexpr int SLOTS = BK / 8;            // 16B slots per LDS row
    constexpr int SMASK = SLOTS - 1;
    constexpr int LOG2S = (BK == 32) ? 2 : 3;
    constexpr int RSH   = (BK == 32) ? 1 : 0;  // row-phase shift for swizzle
    constexpr int ITS = BK / 16;             // staging iters (256 thr, 16B each)
    __shared__ f16 SM[512 * BK];             // 2 bufs x (As 128xBK | Bs 128xBK); reused as Cs
    f16* Cs = SM;                            // BK>=32 -> >=32KB, fits 128x128 f16 C-tile
    // bijective XCD remap (m204), then row-major decode: consecutive wg share A-panel
    const int nwg = gridDim.x, orig = blockIdx.x;
    const int q = nwg >> 3, rm = nwg & 7;
    const int xcd = orig & 7, loc = orig >> 3;
    const int wg = (xcd < rm ? xcd * (q + 1) : rm * (q + 1) + (xcd - rm) * q) + loc;
    const int rowT = wg / CT, colT = wg - rowT * CT;
    const int row0 = rowT * 128, col0 = colT * 128;

    const int tid = threadIdx.x;
    const int wave = tid >> 6, lane = tid & 63;
    const int wr = wave >> 1, wc = wave & 1;
    const int lo16 = lane & 15, hi4 = lane >> 4;

    const bool PM = (MODE == 0) && (col0 >= 2048) && (col0 < 4096);  // block-uniform

    f32x4 acc[4][4] = {};

    auto stage = [&](int buf, int k0) {
        f16* As = SM + buf * 256 * BK;
        f16* Bs = As + 128 * BK;
#pragma unroll
        for (int it = 0; it < ITS; ++it) {
            int c = it * 256 + wave * 64 + lane;   // 16B chunk id, lane-contiguous per wave
            int r = c >> LOG2S, sl = c & SMASK;
            int kc = ((sl ^ ((r >> RSH) & SMASK)) << 3);  // pre-swizzled global source (rule #21)
            int brow = col0 + r;
            if (PM) {                               // W3/W4 16-col interleave remap
                int qc = col0 - 2048 + r;
                int grp = qc >> 5, q2 = qc & 31;
                brow = (q2 < 16) ? (2048 + grp * 16 + q2) : (3072 + grp * 16 + (q2 - 16));
            }
            gload_lds16(A  + (size_t)(row0 + r) * K + (k0 + kc), &As[c * 8]);
            gload_lds16(Bt + (size_t)brow * K + (k0 + kc), &Bs[c * 8]);
        }
    };

    const int nt = K / BK;
    stage(0, 0);
    __syncthreads();                               // buf0 ready
    for (int t = 0; t < nt; ++t) {
        if (t + 1 < nt) stage((t + 1) & 1, (t + 1) * BK);   // prefetch in flight during MFMA
        const f16* As = SM + (t & 1) * 256 * BK;
        const f16* Bs = As + 128 * BK;
#pragma unroll
        for (int kk = 0; kk < BK; kk += 32) {
            const int s0 = (kk >> 3) + hi4;
            f16x8 af[4], bf[4];
#pragma unroll
            for (int m = 0; m < 4; ++m) {
                int row = wr * 64 + m * 16 + lo16;
                int sw = s0 ^ ((row >> RSH) & SMASK);   // read-side swizzle (same involution)
                af[m] = *(const f16x8*)&As[row * BK + (sw << 3)];
            }
#pragma unroll
            for (int n = 0; n < 4; ++n) {
                int row = wc * 64 + n * 16 + lo16;
                int sw = s0 ^ ((row >> RSH) & SMASK);
                bf[n] = *(const f16x8*)&Bs[row * BK + (sw << 3)];
            }
#pragma unroll
            for (int m = 0; m < 4; ++m)
#pragma unroll
                for (int n = 0; n < 4; ++n)
                    acc[m][n] = __builtin_amdgcn_mfma_f32_16x16x32_f16(af[m], bf[n], acc[m][n], 0, 0, 0);
        }
        __syncthreads();   // single barrier/iter: drains prefetch (covered by MFMA) + seals reads
    }

    if (PM) {
        // p-fusion epilogue: p = sigmoid(acc_even + b3) * tanh(acc_odd + b4), 128x64 tile
        const int c = (col0 - 2048) >> 7;
#pragma unroll
        for (int pair = 0; pair < 2; ++pair) {
            int colg = 16 * (4 * c + 2 * wc + pair) + lo16;   // global Pt col
            float bi = bb3[colg], bg = bb4[colg];
            int colL = wc * 32 + pair * 16 + lo16;            // local col in 64-wide tile
#pragma unroll
            for (int m = 0; m < 4; ++m)
#pragma unroll
                for (int j = 0; j < 4; ++j) {
                    int row = wr * 64 + m * 16 + hi4 * 4 + j;
                    float pi = sigmoid_fast(acc[m][2 * pair][j] + bi);
                    float pg = tanh_fast(acc[m][2 * pair + 1][j] + bg);
                    Cs[row * 64 + 8 * ((colL >> 3) ^ (row & 7)) + (colL & 7)] = (f16)(pi * pg);
                }
        }
        __syncthreads();
        const int pcol0 = (col0 - 2048) >> 1;
#pragma unroll
        for (int it = 0; it < 4; ++it) {
            int idx = it * 256 + tid;
            int row = idx >> 3, ch = idx & 7;
            f16x8 v = *(const f16x8*)&Cs[row * 64 + 8 * (ch ^ (row & 7))];
            *(f16x8*)&O1[(size_t)(row0 + row) * 1024 + pcol0 + ch * 8] = v;
        }
        return;
    }

    // block-uniform epilogue params (non-interleaved tiles)
    f16* Oe; size_t ostr; const float* bp; int act;
    if (MODE == 1)          { Oe = O0 + col0;          ostr = 1024; bp = bb1 + col0;          act = 2; }
    else if (col0 < 2048)   { Oe = O0 + col0;          ostr = 2048; bp = bb1 + col0;          act = 0; }
    else                    { Oe = O3 + (col0 - 4096); ostr = 1024; bp = nullptr;             act = 0; }

    if (act == 0) cs_write<0>(Cs, acc, bp, wr, wc, lo16, hi4);
    else          cs_write<2>(Cs, acc, bp, wr, wc, lo16, hi4);
    __syncthreads();

    // coalesced store: 8 x f16x8 per thread, 1KB contiguous per wave
#pragma unroll
    for (int it = 0; it < 8; ++it) {
        int idx = it * 256 + tid;
        int row = idx >> 4, ch = idx & 15;
        int sw = ch ^ (row & 15);
        f16x8 v = *(const f16x8*)&Cs[row * 128 + sw * 8];
        *(f16x8*)&Oe[(size_t)(row0 + row) * ostr + ch * 8] = v;
    }
}

// ---------------- scan over T, XCD-sliced: block = (batch b, unit-slice x of 128) ----------------
// blockIdx = b*8 + x -> round-robin dispatch pins slice x to XCD x (L2 affinity).
// Branch-free 16-slot / 12-deep static software pipeline: loads for step t+12 are issued
// unconditionally (token buffer zero-padded) 12 steps before use; all slot indices are
// compile-time constants (main loop unrolled by 16 so t&15 == k).
__global__ __launch_bounds__(64) void scan_slice_kernel(
    const int* __restrict__ tokens, const f16* __restrict__ Mt, const f16* __restrict__ Pt,
    const f16* __restrict__ Ut, const float* __restrict__ state0,
    const float* __restrict__ Wout, float* __restrict__ partial) {
    __shared__ int toks[256];
    const int bid = blockIdx.x;
    const int b = bid >> 3, x = bid & 7;
    const int lane = threadIdx.x;
    for (int t = lane; t < 256; t += 64) toks[t] = (t < 250) ? tokens[b * 250 + t] : 0;
    __syncthreads();

    const int u0 = x * 128 + lane * 2;
    float2 sv = *(const float2*)&state0[(size_t)b * 1024 + u0];
    float s0 = sv.x, s1 = sv.y;

    f16x2 m[16], p[16], u[16];
#pragma unroll
    for (int k = 0; k < 12; ++k) {   // preload t=0..11 into slots 0..11
        size_t nb = (size_t)toks[k] * 1024 + u0;
        m[k] = *(const f16x2*)&Mt[nb];
        p[k] = *(const f16x2*)&Pt[nb];
        u[k] = *(const f16x2*)&Ut[nb];
    }

    // main: t = 0..239 (15 x 16 unrolled, all slots static); loads target t+12
    for (int tb = 0; tb < 240; tb += 16) {
#pragma unroll
        for (int k = 0; k < 16; ++k) {
            const int ls = (k + 12) & 15;        // compile-time slot for t+12
            size_t nb = (size_t)toks[tb + k + 12] * 1024 + u0;
            m[ls] = *(const f16x2*)&Mt[nb];
            p[ls] = *(const f16x2*)&Pt[nb];
            u[ls] = *(const f16x2*)&Ut[nb];
            float y0 = fmaxf((float)m[k][0] * s0 + (float)p[k][0], 0.f);
            s0 = fmaxf((float)u[k][0] + y0, 0.f);
            float y1 = fmaxf((float)m[k][1] * s1 + (float)p[k][1], 0.f);
            s1 = fmaxf((float)u[k][1] + y1, 0.f);
        }
    }
    // tail: t = 240..249 (slots 0..9, already loaded at t=228..237)
#pragma unroll
    for (int k = 0; k < 10; ++k) {
        float y0 = fmaxf((float)m[k][0] * s0 + (float)p[k][0], 0.f);
        s0 = fmaxf((float)u[k][0] + y0, 0.f);
        float y1 = fmaxf((float)m[k][1] * s1 + (float)p[k][1], 0.f);
        s1 = fmaxf((float)u[k][1] + y1, 0.f);
    }

    float2 wv = *(const float2*)&Wout[u0];
    float part = s0 * wv.x + s1 * wv.y;
#pragma unroll
    for (int o = 32; o > 0; o >>= 1) part += __shfl_down(part, o, 64);
    if (lane == 0) partial[bid] = part;
}

// ---------------- final reduce: out[b] = sigmoid(sum_x partial[b*8+x] + bout) ----------------
__global__ __launch_bounds__(256) void final_kernel(const float* __restrict__ partial,
                                                    const float* __restrict__ bout,
                                                    float* __restrict__ out) {
    int b = threadIdx.x;
    float tot = bout[0];
#pragma unroll
    for (int w = 0; w < 8; ++w) tot += partial[b * 8 + w];
    out[b] = sigmoid_fast(tot);
}

extern "C" void kernel_launch(void* const* d_in, const int* in_sizes, int n_in,
                              void* d_out, int out_size, void* d_ws, size_t ws_size,
                              hipStream_t stream) {
    const int*   tokens = (const int*)  d_in[0];
    const float* emb    = (const float*)d_in[1];
    const float* W1     = (const float*)d_in[2];
    const float* b1     = (const float*)d_in[3];
    const float* W2     = (const float*)d_in[4];
    const float* b2     = (const float*)d_in[5];
    const float* W3     = (const float*)d_in[6];
    const float* b3     = (const float*)d_in[7];
    const float* W4     = (const float*)d_in[8];
    const float* b4     = (const float*)d_in[9];
    const float* W5     = (const float*)d_in[10];
    const float* Wout   = (const float*)d_in[11];
    const float* bout   = (const float*)d_in[12];
    const float* state0 = (const float*)d_in[13];
    float* out = (float*)d_out;

    const int RP = 10112;  // 79 * 128, padded vocab rows

    char* ws = (char*)d_ws;
    size_t off = 0;
    auto alloc = [&](size_t bytes) -> void* {
        void* p = ws + off;
        off += (bytes + 255) & ~(size_t)255;
        return p;
    };
    f16* WtQ = (f16*)alloc((size_t)5120 * 256 * 2);   // W1|W3|W4|W5 transposed [5120][256]
    f16* Wt2 = (f16*)alloc((size_t)1024 * 2048 * 2);
    f16* E   = (f16*)alloc((size_t)RP * 256 * 2);
    f16* Rb  = (f16*)alloc((size_t)RP * 2048 * 2);
    f16* Mt  = (f16*)alloc((size_t)RP * 1024 * 2);
    f16* Pt  = (f16*)alloc((size_t)RP * 1024 * 2);
    f16* Ut  = (f16*)alloc((size_t)RP * 1024 * 2);
    float* partial = (float*)alloc((size_t)2048 * 4);
    (void)ws_size; (void)in_sizes; (void)n_in; (void)out_size;

    // weights -> f16 transposed [N][K] (LDS-tiled, coalesced both ways)
    tpose_kernel<<<dim3(4, 32),  256, 0, stream>>>(W1, WtQ,               256, 2048);
    tpose_kernel<<<dim3(4, 16),  256, 0, stream>>>(W3, WtQ + 2048 * 256,  256, 1024);
    tpose_kernel<<<dim3(4, 16),  256, 0, stream>>>(W4, WtQ + 3072 * 256,  256, 1024);
    tpose_kernel<<<dim3(4, 16),  256, 0, stream>>>(W5, WtQ + 4096 * 256,  256, 1024);
    tpose_kernel<<<dim3(32, 16), 256, 0, stream>>>(W2, Wt2,              2048, 1024);
    ecast_kernel<<<RP / 4, 256, 0, stream>>>(emb, E);

    // fused per-vocab tables: E @ [W1 | W3/W4 interleaved | W5]  (N=5120, K=256)
    gemm_main<0, 32><<<(RP / 128) * (5120 / 128), 256, 0, stream>>>(
        E, WtQ, 5120, 256, 5120 / 128, b1, b3, b4, Rb, Pt, Ut);
    // Mt = tanh(relu(...) @ W2 + b2)  (N=1024, K=2048)  -- BK=32: whole grid co-resident
    gemm_main<1, 32><<<(RP / 128) * (1024 / 128), 256, 0, stream>>>(
        Rb, Wt2, 1024, 2048, 1024 / 128, b2, nullptr, nullptr, Mt, nullptr, nullptr);

    // scan (XCD-sliced, deep-pipelined) + final projection reduce
    scan_slice_kernel<<<2048, 64, 0, stream>>>(tokens, Mt, Pt, Ut, state0, Wout, partial);
    final_kernel<<<1, 256, 0, stream>>>(partial, bout, out);
}